// Round 1
// baseline (748.366 us; speedup 1.0000x reference)
//
#include <hip/hip_runtime.h>
#include <hip/hip_bf16.h>
#include <math.h>

// Problem constants (reference file)
#define NB     65536   // batch
#define SDIM   20000
#define DDIM   300
#define PFN    12
#define LFN    8
#define ADIM   8
#define ICH    21      // PF + LF + 1
#define TPB    64
#define FSTRIDE 194    // 9*21=189 bf16 padded to 194 (97 dwords, odd -> conflict-free)

__device__ __forceinline__ float lrelu(float v) { return v > 0.0f ? v : 0.2f * v; }

__launch_bounds__(TPB, 1)
__global__ void disc_kernel(
    const int* __restrict__ state, const int* __restrict__ des,
    const int* __restrict__ act,
    const int* __restrict__ asp_g,   // action_state_pad (S,9)
    const int* __restrict__ pmp_g,   // policy_mask_pad  (S,9)
    const float* __restrict__ path_feature,  // (S,D,12)
    const float* __restrict__ link_feature,  // (S,8)
    const float* __restrict__ w1, const float* __restrict__ b1,   // conv1 (20,21,3,3)
    const float* __restrict__ w2, const float* __restrict__ b2,   // conv2 (30,20,2,2)
    const float* __restrict__ fw1, const float* __restrict__ fb1, // (120,38)
    const float* __restrict__ fw2, const float* __restrict__ fb2, // (84,120)
    const float* __restrict__ fw3, const float* __restrict__ fb3, // (1,84)
    float* __restrict__ out, int n)
{
    __shared__ __hip_bfloat16 feat[TPB * FSTRIDE];
    const int tid = threadIdx.x;
    const int gid = blockIdx.x * TPB + tid;
    if (gid >= n) return;

    const int s  = state[gid];
    const int d  = des[gid];
    const int ai = act[gid];

    static constexpr int NEW_IDX[9] = {7, 0, 1, 6, 8, 2, 5, 4, 3};

    const int* asp = asp_g + s * 9;
    const int* pmp = pmp_g + s * 9;
    __hip_bfloat16* fbase = feat + tid * FSTRIDE;

    // ---- Gather: 9 positions x (12 path + 8 link + 1 mask) -> per-thread LDS (bf16)
#pragma unroll
    for (int p = 0; p < 9; ++p) {
        const int a  = NEW_IDX[p];
        const int na = asp[a];
        const float m = (float)pmp[a];
        const float4* pf = (const float4*)(path_feature + (na * DDIM + d) * PFN);
        const float4  v0 = pf[0], v1 = pf[1], v2 = pf[2];
        const float4* lf = (const float4*)(link_feature + na * LFN);
        const float4  u0 = lf[0], u1 = lf[1];
        __hip_bfloat16* dst = fbase + p * ICH;
        dst[0]  = __float2bfloat16(v0.x);  dst[1]  = __float2bfloat16(v0.y);
        dst[2]  = __float2bfloat16(v0.z);  dst[3]  = __float2bfloat16(v0.w);
        dst[4]  = __float2bfloat16(v1.x);  dst[5]  = __float2bfloat16(v1.y);
        dst[6]  = __float2bfloat16(v1.z);  dst[7]  = __float2bfloat16(v1.w);
        dst[8]  = __float2bfloat16(v2.x);  dst[9]  = __float2bfloat16(v2.y);
        dst[10] = __float2bfloat16(v2.z);  dst[11] = __float2bfloat16(v2.w);
        dst[12] = __float2bfloat16(u0.x);  dst[13] = __float2bfloat16(u0.y);
        dst[14] = __float2bfloat16(u0.z);  dst[15] = __float2bfloat16(u0.w);
        dst[16] = __float2bfloat16(u1.x);  dst[17] = __float2bfloat16(u1.y);
        dst[18] = __float2bfloat16(u1.z);  dst[19] = __float2bfloat16(u1.w);
        dst[20] = __float2bfloat16(m);
    }
    // No barrier: each thread only reads its own LDS region (lgkmcnt orders it).

    // ---- conv1 (pad=1) : out[20][3][3], ic loop rolled, everything else unrolled
    float o[20][9];
#pragma unroll
    for (int oc = 0; oc < 20; ++oc) {
        const float bb = b1[oc];
#pragma unroll
        for (int p = 0; p < 9; ++p) o[oc][p] = bb;
    }

#pragma unroll 1
    for (int ic = 0; ic < ICH; ++ic) {
        float fv[9];
#pragma unroll
        for (int p = 0; p < 9; ++p)
            fv[p] = __bfloat162float(fbase[p * ICH + ic]);
#pragma unroll
        for (int oc = 0; oc < 20; ++oc) {
            const float* w = w1 + (oc * ICH + ic) * 9;
#pragma unroll
            for (int t = 0; t < 9; ++t) {
                const int ky = t / 3 - 1, kx = t % 3 - 1;
                const float wv = w[t];
#pragma unroll
                for (int y = 0; y < 3; ++y) {
                    const int iy = y + ky;
                    if (iy < 0 || iy > 2) continue;
#pragma unroll
                    for (int x = 0; x < 3; ++x) {
                        const int ix = x + kx;
                        if (ix < 0 || ix > 2) continue;
                        o[oc][y * 3 + x] = fmaf(wv, fv[iy * 3 + ix], o[oc][y * 3 + x]);
                    }
                }
            }
        }
    }

    // ---- lrelu + 2x2 maxpool (stride 1) -> pooled[20][4]
    float pooled[20][4];
#pragma unroll
    for (int oc = 0; oc < 20; ++oc) {
        float v[9];
#pragma unroll
        for (int p = 0; p < 9; ++p) v[p] = lrelu(o[oc][p]);
        pooled[oc][0] = fmaxf(fmaxf(v[0], v[1]), fmaxf(v[3], v[4]));
        pooled[oc][1] = fmaxf(fmaxf(v[1], v[2]), fmaxf(v[4], v[5]));
        pooled[oc][2] = fmaxf(fmaxf(v[3], v[4]), fmaxf(v[6], v[7]));
        pooled[oc][3] = fmaxf(fmaxf(v[4], v[5]), fmaxf(v[7], v[8]));
    }

    // ---- conv2 2x2 VALID -> x30[30], lrelu
    float x30[30];
#pragma unroll
    for (int j = 0; j < 30; ++j) {
        float acc = b2[j];
#pragma unroll
        for (int oc = 0; oc < 20; ++oc) {
            const float* w = w2 + j * 80 + oc * 4;
#pragma unroll
            for (int t = 0; t < 4; ++t)
                acc = fmaf(w[t], pooled[oc][t], acc);
        }
        x30[j] = lrelu(acc);
    }

    // ---- fc1 (38->120) fused with fc2 (120->84): h1 never materialized
    float acc3[84];
#pragma unroll
    for (int i = 0; i < 84; ++i) acc3[i] = fb2[i];

#pragma unroll 1
    for (int j = 0; j < 120; ++j) {
        const float* w = fw1 + j * 38;
        float acc = fb1[j] + w[30 + ai];   // one-hot(act) contribution
#pragma unroll
        for (int k = 0; k < 30; ++k)
            acc = fmaf(w[k], x30[k], acc);
        const float h = lrelu(acc);
#pragma unroll
        for (int i = 0; i < 84; ++i)
            acc3[i] = fmaf(fw2[i * 120 + j], h, acc3[i]);
    }

    // ---- fc3 (84->1) + sigmoid
    float z = fb3[0];
#pragma unroll
    for (int i = 0; i < 84; ++i)
        z = fmaf(fw3[i], lrelu(acc3[i]), z);

    out[gid] = 1.0f / (1.0f + __expf(-z));
}

extern "C" void kernel_launch(void* const* d_in, const int* in_sizes, int n_in,
                              void* d_out, int out_size, void* d_ws, size_t ws_size,
                              hipStream_t stream) {
    const int*   state = (const int*)d_in[0];
    const int*   des   = (const int*)d_in[1];
    const int*   act   = (const int*)d_in[2];
    const int*   asp   = (const int*)d_in[3];
    const int*   pmp   = (const int*)d_in[4];
    const float* pathf = (const float*)d_in[5];
    const float* linkf = (const float*)d_in[6];
    const float* w1    = (const float*)d_in[7];
    const float* b1    = (const float*)d_in[8];
    const float* w2    = (const float*)d_in[9];
    const float* b2    = (const float*)d_in[10];
    const float* fw1   = (const float*)d_in[11];
    const float* fb1   = (const float*)d_in[12];
    const float* fw2   = (const float*)d_in[13];
    const float* fb2   = (const float*)d_in[14];
    const float* fw3   = (const float*)d_in[15];
    const float* fb3   = (const float*)d_in[16];

    const int n = in_sizes[0];
    dim3 grid((n + TPB - 1) / TPB), block(TPB);
    hipLaunchKernelGGL(disc_kernel, grid, block, 0, stream,
                       state, des, act, asp, pmp, pathf, linkf,
                       w1, b1, w2, b2, fw1, fb1, fw2, fb2, fw3, fb3,
                       (float*)d_out, n);
}